// Round 7
// baseline (160.612 us; speedup 1.0000x reference)
//
#include <hip/hip_runtime.h>

// Sparse deconv (27-tap, 64->96ch) + BN + ReLU on MI355X.
// 2-D wave split: each wave = 64 rows x 48 cols (acc 48 AGPR, B 24 VGPR)
// -> ~165 regs -> 3 waves/SIMD for latency hiding. Barrier-free main loop,
// exec-masked sparse gathers, 1-deep srcmap+gather prefetch, bf16 staging.

#define N_VOX   200000
#define INC     64
#define OUTC    96
#define NOFF    26
#define NBLK    1563          // ceil(200000 / 128)
#define NPAD    200192        // >= NBLK*128, padded srcmap stride
#define EPSV    1e-5f

using bf16x8 = __attribute__((ext_vector_type(8))) short;
using f32x4  = __attribute__((ext_vector_type(4))) float;

__device__ inline unsigned short f2bf(float x) {
    union { float f; unsigned u; } v; v.f = x;
    unsigned r = (v.u + 0x7FFFu + ((v.u >> 16) & 1u)) >> 16;
    return (unsigned short)r;
}

__global__ void fill_src_kernel(const int* __restrict__ in_idx,
                                const int* __restrict__ out_idx,
                                int P, int* __restrict__ srcmap) {
    int idx = blockIdx.x * blockDim.x + threadIdx.x;
    if (idx >= NOFF * P) return;
    int dst = out_idx[idx];
    if (dst >= N_VOX) return;            // padded sink entries
    int k = idx / P;
    srcmap[(size_t)k * NPAD + dst] = in_idx[idx];
}

// Weights -> bf16, B-fragment order: Wb[m][s][ct][lane][e],
// k = s*32 + (lane>>4)*8 + e, col = ct*16 + (lane&15).
__global__ void wprep_kernel(const float* __restrict__ Wc,
                             const float* __restrict__ Woff,
                             unsigned short* __restrict__ Wb) {
    int t = blockIdx.x * blockDim.x + threadIdx.x;
    if (t >= 27 * 2 * 6 * 64) return;
    int lane = t & 63;
    int g    = t >> 6;              // m*12 + s*6 + ct
    int ct   = g % 6;
    int s    = (g / 6) % 2;
    int m    = g / 12;
    const float* W = (m == 26) ? Wc : (Woff + (size_t)m * INC * OUTC);
    int k0 = s * 32 + (lane >> 4) * 8;
    int c  = ct * 16 + (lane & 15);
    bf16x8 v;
    #pragma unroll
    for (int e = 0; e < 8; ++e)
        v[e] = (short)f2bf(W[(size_t)(k0 + e) * OUTC + c]);
    *(bf16x8*)(Wb + (size_t)t * 8) = v;
}

__global__ void fcvt_kernel(const float* __restrict__ feats,
                            unsigned short* __restrict__ featsb) {
    int i = blockIdx.x * blockDim.x + threadIdx.x;   // one per 8 elems
    if (i >= N_VOX * INC / 8) return;
    const float4* src = (const float4*)feats + (size_t)i * 2;
    float4 f0 = src[0], f1 = src[1];
    bf16x8 v;
    v[0] = (short)f2bf(f0.x); v[1] = (short)f2bf(f0.y);
    v[2] = (short)f2bf(f0.z); v[3] = (short)f2bf(f0.w);
    v[4] = (short)f2bf(f1.x); v[5] = (short)f2bf(f1.y);
    v[6] = (short)f2bf(f1.z); v[7] = (short)f2bf(f1.w);
    *(bf16x8*)(featsb + (size_t)i * 8) = v;
}

// tap order: idx 0 -> center (Wb[26], identity src), idx i>=1 -> offset i-1.
// 4 waves/block: wid>>1 = row group (64 rows), wid&1 = col group (48 cols).
template<int STAGE_BF16>
__global__ __launch_bounds__(256, 3)
void conv_mfma_kernel(const unsigned short* __restrict__ featsb,
                      const unsigned short* __restrict__ Wb,
                      const int* __restrict__ srcmap,
                      float* __restrict__ outf,
                      unsigned short* __restrict__ stg,
                      float* __restrict__ pstats) {
    __shared__ float sred[384];               // stats only (post-loop)

    const int t      = threadIdx.x;
    const int wid    = t >> 6;
    const int lane   = t & 63;
    const int rowgrp = wid >> 1;
    const int colgrp = wid & 1;
    const int blk    = blockIdx.x;
    const int rbase  = blk * 128 + rowgrp * 64;  // this wave's 64 output rows
    const int cbase  = colgrp * 48;              // this wave's 48 output cols
    const int row16  = lane & 15;
    const int kgrp   = lane >> 4;                // 0..3

    f32x4  acc[4][3] = {};
    bf16x8 aC[4][2], aN[4][2];
    int smC[4], smN[4];
    int hasC, hasN;

    // ---- prologue: srcmap for offset 0; gather center rows ----
    #pragma unroll
    for (int rt = 0; rt < 4; ++rt)
        smC[rt] = srcmap[rbase + rt * 16 + row16];
    {
        int h = 0;
        #pragma unroll
        for (int rt = 0; rt < 4; ++rt) {
            int row = rbase + rt * 16 + row16;
            if (__ballot(row < N_VOX)) h |= (1 << rt);
            int src = row < N_VOX ? row : N_VOX;          // pad row = zeros
            const unsigned short* fr = featsb + (size_t)src * INC + kgrp * 8;
            aC[rt][0] = *(const bf16x8*)fr;
            aC[rt][1] = *(const bf16x8*)(fr + 32);
        }
        hasC = __builtin_amdgcn_readfirstlane(h);
    }

    #pragma unroll 1
    for (int idx = 0; idx < 27; ++idx) {
        // 1. srcmap prefetch for offset idx+1 (consumed next iter)
        if (idx < 25) {
            #pragma unroll
            for (int rt = 0; rt < 4; ++rt)
                smN[rt] = srcmap[(size_t)(idx + 1) * NPAD + rbase + rt * 16 + row16];
        }

        // 2. exec-masked gather of A for offset idx (consumed next iter)
        if (idx < 26) {
            int h = 0;
            #pragma unroll
            for (int rt = 0; rt < 4; ++rt) {
                int s = smC[rt];
                if (__ballot(s >= 0)) h |= (1 << rt);
                bf16x8 g0 = {}, g1 = {};
                if (s >= 0) {
                    const unsigned short* fr = featsb + (size_t)s * INC + kgrp * 8;
                    g0 = *(const bf16x8*)fr;
                    g1 = *(const bf16x8*)(fr + 32);
                }
                aN[rt][0] = g0; aN[rt][1] = g1;
            }
            hasN = __builtin_amdgcn_readfirstlane(h);
        } else {
            hasN = 0;
        }

        // 3. B column-slice for current tap -> 24 VGPR (uniform, L1/L2-hit)
        const int m = (idx == 0) ? 26 : idx - 1;
        const unsigned short* wb = Wb + (size_t)m * 6144;
        bf16x8 B0[3], B1[3];
        #pragma unroll
        for (int ct = 0; ct < 3; ++ct) {
            B0[ct] = *(const bf16x8*)(wb + (size_t)(colgrp * 3 + ct) * 512 + lane * 8);
            B1[ct] = *(const bf16x8*)(wb + (size_t)(6 + colgrp * 3 + ct) * 512 + lane * 8);
        }

        // 4. MFMA current tap, per-rt skip
        #pragma unroll
        for (int rt = 0; rt < 4; ++rt) {
            if (hasC & (1 << rt)) {
                #pragma unroll
                for (int ct = 0; ct < 3; ++ct) {
                    acc[rt][ct] = __builtin_amdgcn_mfma_f32_16x16x32_bf16(aC[rt][0], B0[ct], acc[rt][ct], 0, 0, 0);
                    acc[rt][ct] = __builtin_amdgcn_mfma_f32_16x16x32_bf16(aC[rt][1], B1[ct], acc[rt][ct], 0, 0, 0);
                }
            }
        }

        // 5. roll pipeline registers
        #pragma unroll
        for (int rt = 0; rt < 4; ++rt) {
            aC[rt][0] = aN[rt][0]; aC[rt][1] = aN[rt][1];
            smC[rt] = (idx < 25) ? smN[rt] : -1;
        }
        hasC = hasN;
    }

    // ---- BN partial stats: lane -> wave shfl -> LDS cross-wave ----
    float s3[3], q3[3];
    #pragma unroll
    for (int ct = 0; ct < 3; ++ct) {
        float s = 0.f, q = 0.f;
        #pragma unroll
        for (int rt = 0; rt < 4; ++rt) {
            f32x4 a = acc[rt][ct];
            s += a[0] + a[1] + a[2] + a[3];
            q += a[0]*a[0] + a[1]*a[1] + a[2]*a[2] + a[3]*a[3];
        }
        s += __shfl_xor(s, 16); q += __shfl_xor(q, 16);
        s += __shfl_xor(s, 32); q += __shfl_xor(q, 32);
        s3[ct] = s; q3[ct] = q;
    }
    if (lane < 16) {
        #pragma unroll
        for (int ct = 0; ct < 3; ++ct) {
            sred[wid * 48 + ct * 16 + lane]       = s3[ct];
            sred[192 + wid * 48 + ct * 16 + lane] = q3[ct];
        }
    }
    __syncthreads();
    if (t < 96) {
        int cg = t / 48, cc = t % 48;           // wids with this colgrp: cg, 2+cg
        float s = sred[cg * 48 + cc] + sred[(2 + cg) * 48 + cc];
        float q = sred[192 + cg * 48 + cc] + sred[192 + (2 + cg) * 48 + cc];
        pstats[(size_t)t * NBLK + blk] = s;
        pstats[(size_t)(96 + t) * NBLK + blk] = q;
    }

    // ---- store conv output ----
    #pragma unroll
    for (int rt = 0; rt < 4; ++rt) {
        #pragma unroll
        for (int ct = 0; ct < 3; ++ct) {
            #pragma unroll
            for (int j = 0; j < 4; ++j) {
                int row = rbase + rt * 16 + kgrp * 4 + j;
                if (row < N_VOX) {
                    int col = cbase + ct * 16 + row16;
                    if (STAGE_BF16)
                        stg[(size_t)row * OUTC + col] = f2bf(acc[rt][ct][j]);
                    else
                        outf[(size_t)row * OUTC + col] = acc[rt][ct][j];
                }
            }
        }
    }
}

__global__ void stats_reduce_kernel(const float* __restrict__ pstats,
                                    const float* __restrict__ gamma,
                                    const float* __restrict__ beta,
                                    float* __restrict__ scsh) {
    int c = blockIdx.x;               // 0..95
    int t = threadIdx.x;
    float s = 0.f, q = 0.f;
    for (int i = t; i < NBLK; i += 256) {
        s += pstats[(size_t)c * NBLK + i];
        q += pstats[(size_t)(96 + c) * NBLK + i];
    }
    #pragma unroll
    for (int d = 1; d < 64; d <<= 1) {
        s += __shfl_xor(s, d);
        q += __shfl_xor(q, d);
    }
    __shared__ float rs[4], rq[4];
    if ((t & 63) == 0) { rs[t >> 6] = s; rq[t >> 6] = q; }
    __syncthreads();
    if (t == 0) {
        s = rs[0] + rs[1] + rs[2] + rs[3];
        q = rq[0] + rq[1] + rq[2] + rq[3];
        float inv_n = 1.0f / (float)N_VOX;
        float mean = s * inv_n;
        float var  = q * inv_n - mean * mean;
        float sc   = gamma[c] * rsqrtf(var + EPSV);
        scsh[c]      = sc;
        scsh[96 + c] = beta[c] - mean * sc;
    }
}

__global__ void apply_bn_bf16_kernel(const unsigned short* __restrict__ stg,
                                     float* __restrict__ out,
                                     const float* __restrict__ scsh) {
    __shared__ float sc[OUTC], sh[OUTC];
    int t = threadIdx.x;
    if (t < OUTC) { sc[t] = scsh[t]; sh[t] = scsh[96 + t]; }
    __syncthreads();
    const int total8 = N_VOX * OUTC / 8;
    for (int i = blockIdx.x * blockDim.x + t; i < total8; i += gridDim.x * blockDim.x) {
        bf16x8 v = *(const bf16x8*)(stg + (size_t)i * 8);
        int c = (i % 12) * 8;
        float o[8];
        #pragma unroll
        for (int j = 0; j < 8; ++j) {
            union { unsigned u; float f; } w; w.u = (unsigned)(unsigned short)v[j] << 16;
            o[j] = fmaxf(fmaf(w.f, sc[c + j], sh[c + j]), 0.f);
        }
        float4* dst = (float4*)(out + (size_t)i * 8);
        dst[0] = make_float4(o[0], o[1], o[2], o[3]);
        dst[1] = make_float4(o[4], o[5], o[6], o[7]);
    }
}

__global__ void apply_bn_fp32_kernel(float* __restrict__ out,
                                     const float* __restrict__ scsh) {
    __shared__ float sc[OUTC], sh[OUTC];
    int t = threadIdx.x;
    if (t < OUTC) { sc[t] = scsh[t]; sh[t] = scsh[96 + t]; }
    __syncthreads();
    const int total4 = N_VOX * OUTC / 4;
    for (int i = blockIdx.x * blockDim.x + t; i < total4; i += gridDim.x * blockDim.x) {
        float4 v = ((float4*)out)[i];
        int c = (i * 4) % OUTC;
        v.x = fmaxf(fmaf(v.x, sc[c    ], sh[c    ]), 0.f);
        v.y = fmaxf(fmaf(v.y, sc[c + 1], sh[c + 1]), 0.f);
        v.z = fmaxf(fmaf(v.z, sc[c + 2], sh[c + 2]), 0.f);
        v.w = fmaxf(fmaf(v.w, sc[c + 3], sh[c + 3]), 0.f);
        ((float4*)out)[i] = v;
    }
}

extern "C" void kernel_launch(void* const* d_in, const int* in_sizes, int n_in,
                              void* d_out, int out_size, void* d_ws, size_t ws_size,
                              hipStream_t stream) {
    const float* feats   = (const float*)d_in[0];
    const float* Wc      = (const float*)d_in[1];
    const float* Woff    = (const float*)d_in[2];
    const float* gamma   = (const float*)d_in[3];
    const float* beta    = (const float*)d_in[4];
    const int*   in_idx  = (const int*)d_in[5];
    const int*   out_idx = (const int*)d_in[6];
    const int P = in_sizes[5] / NOFF;

    char* w = (char*)d_ws;
    int* srcmap = (int*)w;                   w += (size_t)NOFF * NPAD * 4;    // 20.82 MB
    unsigned short* Wb = (unsigned short*)w; w += (size_t)27 * 6144 * 2;      // 332 KB
    float* pstats = (float*)w;               w += (size_t)192 * NBLK * 4;     // 1.2 MB
    float* scsh = (float*)w;                 w += 256 * 4;
    unsigned short* featsb = (unsigned short*)w;
    w += (size_t)(N_VOX + 1) * INC * 2;                                        // 25.6 MB (+pad row)
    unsigned short* stg = (unsigned short*)w;
    size_t need_stg = (size_t)(w - (char*)d_ws) + (size_t)N_VOX * OUTC * 2;   // +38.4 MB
    bool use_stg = (ws_size >= need_stg);

    hipMemsetAsync(srcmap, 0xFF, (size_t)NOFF * NPAD * 4, stream);
    hipMemsetAsync(featsb + (size_t)N_VOX * INC, 0, INC * 2, stream);         // zero pad row
    fill_src_kernel<<<(NOFF * P + 255) / 256, 256, 0, stream>>>(in_idx, out_idx, P, srcmap);
    wprep_kernel<<<(27 * 2 * 6 * 64 + 255) / 256, 256, 0, stream>>>(Wc, Woff, Wb);
    fcvt_kernel<<<(N_VOX * INC / 8 + 255) / 256, 256, 0, stream>>>(feats, featsb);

    float* out = (float*)d_out;
    if (use_stg) {
        conv_mfma_kernel<1><<<NBLK, 256, 0, stream>>>(featsb, Wb, srcmap, out, stg, pstats);
        stats_reduce_kernel<<<96, 256, 0, stream>>>(pstats, gamma, beta, scsh);
        apply_bn_bf16_kernel<<<2048, 256, 0, stream>>>(stg, out, scsh);
    } else {
        conv_mfma_kernel<0><<<NBLK, 256, 0, stream>>>(featsb, Wb, srcmap, out, stg, pstats);
        stats_reduce_kernel<<<96, 256, 0, stream>>>(pstats, gamma, beta, scsh);
        apply_bn_fp32_kernel<<<2048, 256, 0, stream>>>(out, scsh);
    }
}

// Round 8
// 146.096 us; speedup vs baseline: 1.0994x; 1.0994x over previous
//
#include <hip/hip_runtime.h>

// Sparse deconv (27-tap, 64->96ch) + BN + ReLU on MI355X.
// Barrier-free conv, B-in-registers, ISSUE ORDER FIXED: B loads first each
// iteration so the MFMA's vmcnt wait on B leaves this iteration's gather
// prefetch in flight (true 1-deep pipeline). Exec-mask-free gathers via
// pad-row cndmask; per-rt MFMA skip; bf16 conv-output staging.

#define N_VOX   200000
#define INC     64
#define OUTC    96
#define NOFF    26
#define NBLK    782           // ceil(200000 / 256)
#define NPAD    200192        // NBLK*256, padded srcmap stride
#define EPSV    1e-5f

using bf16x8 = __attribute__((ext_vector_type(8))) short;
using f32x4  = __attribute__((ext_vector_type(4))) float;

__device__ inline unsigned short f2bf(float x) {
    union { float f; unsigned u; } v; v.f = x;
    unsigned r = (v.u + 0x7FFFu + ((v.u >> 16) & 1u)) >> 16;
    return (unsigned short)r;
}

__global__ void fill_src_kernel(const int* __restrict__ in_idx,
                                const int* __restrict__ out_idx,
                                int P, int* __restrict__ srcmap) {
    int idx = blockIdx.x * blockDim.x + threadIdx.x;
    if (idx >= NOFF * P) return;
    int dst = out_idx[idx];
    if (dst >= N_VOX) return;            // padded sink entries
    int k = idx / P;
    srcmap[(size_t)k * NPAD + dst] = in_idx[idx];
}

// Weights -> bf16, B-fragment order: Wb[m][s][ct][lane][e],
// k = s*32 + (lane>>4)*8 + e, col = ct*16 + (lane&15).
__global__ void wprep_kernel(const float* __restrict__ Wc,
                             const float* __restrict__ Woff,
                             unsigned short* __restrict__ Wb) {
    int t = blockIdx.x * blockDim.x + threadIdx.x;
    if (t >= 27 * 2 * 6 * 64) return;
    int lane = t & 63;
    int g    = t >> 6;              // m*12 + s*6 + ct
    int ct   = g % 6;
    int s    = (g / 6) % 2;
    int m    = g / 12;
    const float* W = (m == 26) ? Wc : (Woff + (size_t)m * INC * OUTC);
    int k0 = s * 32 + (lane >> 4) * 8;
    int c  = ct * 16 + (lane & 15);
    bf16x8 v;
    #pragma unroll
    for (int e = 0; e < 8; ++e)
        v[e] = (short)f2bf(W[(size_t)(k0 + e) * OUTC + c]);
    *(bf16x8*)(Wb + (size_t)t * 8) = v;
}

__global__ void fcvt_kernel(const float* __restrict__ feats,
                            unsigned short* __restrict__ featsb) {
    int i = blockIdx.x * blockDim.x + threadIdx.x;   // one per 8 elems
    if (i >= N_VOX * INC / 8) return;
    const float4* src = (const float4*)feats + (size_t)i * 2;
    float4 f0 = src[0], f1 = src[1];
    bf16x8 v;
    v[0] = (short)f2bf(f0.x); v[1] = (short)f2bf(f0.y);
    v[2] = (short)f2bf(f0.z); v[3] = (short)f2bf(f0.w);
    v[4] = (short)f2bf(f1.x); v[5] = (short)f2bf(f1.y);
    v[6] = (short)f2bf(f1.z); v[7] = (short)f2bf(f1.w);
    *(bf16x8*)(featsb + (size_t)i * 8) = v;
}

// tap order: idx 0 -> center (Wb[26], identity src), idx i>=1 -> offset i-1.
template<int STAGE_BF16>
__global__ __launch_bounds__(256, 2)
void conv_mfma_kernel(const unsigned short* __restrict__ featsb,
                      const unsigned short* __restrict__ Wb,
                      const int* __restrict__ srcmap,
                      float* __restrict__ outf,
                      unsigned short* __restrict__ stg,
                      float* __restrict__ pstats) {
    __shared__ float sred[768];               // stats only (post-loop)

    const int t     = threadIdx.x;
    const int wid   = t >> 6;
    const int lane  = t & 63;
    const int blk   = blockIdx.x;
    const int rbase = blk * 256 + wid * 64;   // this wave's 64 output rows
    const int row16 = lane & 15;
    const int kgrp  = lane >> 6 ? 0 : (lane >> 4);   // 0..3 (lane>>4)

    f32x4  acc[4][6] = {};
    bf16x8 aC[4][2], aN[4][2];
    int smC[4], smN[4];
    int hasC, hasN;

    // ---- prologue: srcmap for tap 1 (offset 0); gather center rows ----
    #pragma unroll
    for (int rt = 0; rt < 4; ++rt)
        smC[rt] = srcmap[rbase + rt * 16 + row16];
    #pragma unroll
    for (int rt = 0; rt < 4; ++rt) {
        int row = rbase + rt * 16 + row16;
        int src = row < N_VOX ? row : N_VOX;              // pad row = zeros
        const unsigned short* fr = featsb + (size_t)src * INC + kgrp * 8;
        aC[rt][0] = *(const bf16x8*)fr;
        aC[rt][1] = *(const bf16x8*)(fr + 32);
    }
    hasC = 0xF;

    #pragma unroll 1
    for (int idx = 0; idx < 27; ++idx) {
        // 1. B for CURRENT tap -> registers, ISSUED FIRST (oldest in queue):
        //    the MFMA's wait on B then leaves the younger srcmap+gather
        //    prefetch loads outstanding across the iteration boundary.
        const unsigned short* wb = Wb + (size_t)(idx == 0 ? 26 : idx - 1) * 6144;
        bf16x8 B0[6], B1[6];
        #pragma unroll
        for (int ct = 0; ct < 6; ++ct) {
            B0[ct] = *(const bf16x8*)(wb + (size_t)ct * 512 + lane * 8);
            B1[ct] = *(const bf16x8*)(wb + (size_t)(6 + ct) * 512 + lane * 8);
        }

        // 2. srcmap prefetch for tap idx+2 (offset idx+1)
        if (idx < 25) {
            #pragma unroll
            for (int rt = 0; rt < 4; ++rt)
                smN[rt] = srcmap[(size_t)(idx + 1) * NPAD + rbase + rt * 16 + row16];
        }

        // 3. gather A for tap idx+1 (offset idx): unconditional issue,
        //    inactive lanes read the zeroed pad row (L1-resident).
        if (idx < 26) {
            int h = 0;
            #pragma unroll
            for (int rt = 0; rt < 4; ++rt) {
                int s = smC[rt];
                if (__ballot(s >= 0)) h |= (1 << rt);
                int src = s >= 0 ? s : N_VOX;
                const unsigned short* fr = featsb + (size_t)src * INC + kgrp * 8;
                aN[rt][0] = *(const bf16x8*)fr;
                aN[rt][1] = *(const bf16x8*)(fr + 32);
            }
            hasN = __builtin_amdgcn_readfirstlane(h);
        } else {
            hasN = 0;
        }

        // 4. MFMA current tap, per-rt skip
        #pragma unroll
        for (int rt = 0; rt < 4; ++rt) {
            if (hasC & (1 << rt)) {
                #pragma unroll
                for (int ct = 0; ct < 6; ++ct) {
                    acc[rt][ct] = __builtin_amdgcn_mfma_f32_16x16x32_bf16(aC[rt][0], B0[ct], acc[rt][ct], 0, 0, 0);
                    acc[rt][ct] = __builtin_amdgcn_mfma_f32_16x16x32_bf16(aC[rt][1], B1[ct], acc[rt][ct], 0, 0, 0);
                }
            }
        }

        // 5. roll pipeline registers
        #pragma unroll
        for (int rt = 0; rt < 4; ++rt) {
            aC[rt][0] = aN[rt][0]; aC[rt][1] = aN[rt][1];
            smC[rt] = (idx < 25) ? smN[rt] : -1;
        }
        hasC = hasN;
    }

    // ---- BN partial stats: lane -> wave shfl -> LDS cross-wave ----
    float s6[6], q6[6];
    #pragma unroll
    for (int ct = 0; ct < 6; ++ct) {
        float s = 0.f, q = 0.f;
        #pragma unroll
        for (int rt = 0; rt < 4; ++rt) {
            f32x4 a = acc[rt][ct];
            s += a[0] + a[1] + a[2] + a[3];
            q += a[0]*a[0] + a[1]*a[1] + a[2]*a[2] + a[3]*a[3];
        }
        s += __shfl_xor(s, 16); q += __shfl_xor(q, 16);
        s += __shfl_xor(s, 32); q += __shfl_xor(q, 32);
        s6[ct] = s; q6[ct] = q;
    }
    if (lane < 16) {
        #pragma unroll
        for (int ct = 0; ct < 6; ++ct) {
            sred[wid * 96 + ct * 16 + lane]       = s6[ct];
            sred[384 + wid * 96 + ct * 16 + lane] = q6[ct];
        }
    }
    __syncthreads();
    if (t < 96) {
        float s = sred[t] + sred[96 + t] + sred[192 + t] + sred[288 + t];
        pstats[(size_t)t * NBLK + blk] = s;
    } else if (t < 192) {
        int c = t - 96;
        float q = sred[384 + c] + sred[480 + c] + sred[576 + c] + sred[672 + c];
        pstats[(size_t)(96 + c) * NBLK + blk] = q;
    }

    // ---- store conv output ----
    #pragma unroll
    for (int rt = 0; rt < 4; ++rt) {
        #pragma unroll
        for (int ct = 0; ct < 6; ++ct) {
            #pragma unroll
            for (int j = 0; j < 4; ++j) {
                int row = rbase + rt * 16 + kgrp * 4 + j;
                if (row < N_VOX) {
                    if (STAGE_BF16)
                        stg[(size_t)row * OUTC + ct * 16 + row16] = f2bf(acc[rt][ct][j]);
                    else
                        outf[(size_t)row * OUTC + ct * 16 + row16] = acc[rt][ct][j];
                }
            }
        }
    }
}

__global__ void stats_reduce_kernel(const float* __restrict__ pstats,
                                    const float* __restrict__ gamma,
                                    const float* __restrict__ beta,
                                    float* __restrict__ scsh) {
    int c = blockIdx.x;               // 0..95
    int t = threadIdx.x;
    float s = 0.f, q = 0.f;
    for (int i = t; i < NBLK; i += 256) {
        s += pstats[(size_t)c * NBLK + i];
        q += pstats[(size_t)(96 + c) * NBLK + i];
    }
    #pragma unroll
    for (int d = 1; d < 64; d <<= 1) {
        s += __shfl_xor(s, d);
        q += __shfl_xor(q, d);
    }
    __shared__ float rs[4], rq[4];
    if ((t & 63) == 0) { rs[t >> 6] = s; rq[t >> 6] = q; }
    __syncthreads();
    if (t == 0) {
        s = rs[0] + rs[1] + rs[2] + rs[3];
        q = rq[0] + rq[1] + rq[2] + rq[3];
        float inv_n = 1.0f / (float)N_VOX;
        float mean = s * inv_n;
        float var  = q * inv_n - mean * mean;
        float sc   = gamma[c] * rsqrtf(var + EPSV);
        scsh[c]      = sc;
        scsh[96 + c] = beta[c] - mean * sc;
    }
}

__global__ void apply_bn_bf16_kernel(const unsigned short* __restrict__ stg,
                                     float* __restrict__ out,
                                     const float* __restrict__ scsh) {
    __shared__ float sc[OUTC], sh[OUTC];
    int t = threadIdx.x;
    if (t < OUTC) { sc[t] = scsh[t]; sh[t] = scsh[96 + t]; }
    __syncthreads();
    const int total8 = N_VOX * OUTC / 8;
    for (int i = blockIdx.x * blockDim.x + t; i < total8; i += gridDim.x * blockDim.x) {
        bf16x8 v = *(const bf16x8*)(stg + (size_t)i * 8);
        int c = (i % 12) * 8;
        float o[8];
        #pragma unroll
        for (int j = 0; j < 8; ++j) {
            union { unsigned u; float f; } w; w.u = (unsigned)(unsigned short)v[j] << 16;
            o[j] = fmaxf(fmaf(w.f, sc[c + j], sh[c + j]), 0.f);
        }
        float4* dst = (float4*)(out + (size_t)i * 8);
        dst[0] = make_float4(o[0], o[1], o[2], o[3]);
        dst[1] = make_float4(o[4], o[5], o[6], o[7]);
    }
}

__global__ void apply_bn_fp32_kernel(float* __restrict__ out,
                                     const float* __restrict__ scsh) {
    __shared__ float sc[OUTC], sh[OUTC];
    int t = threadIdx.x;
    if (t < OUTC) { sc[t] = scsh[t]; sh[t] = scsh[96 + t]; }
    __syncthreads();
    const int total4 = N_VOX * OUTC / 4;
    for (int i = blockIdx.x * blockDim.x + t; i < total4; i += gridDim.x * blockDim.x) {
        float4 v = ((float4*)out)[i];
        int c = (i * 4) % OUTC;
        v.x = fmaxf(fmaf(v.x, sc[c    ], sh[c    ]), 0.f);
        v.y = fmaxf(fmaf(v.y, sc[c + 1], sh[c + 1]), 0.f);
        v.z = fmaxf(fmaf(v.z, sc[c + 2], sh[c + 2]), 0.f);
        v.w = fmaxf(fmaf(v.w, sc[c + 3], sh[c + 3]), 0.f);
        ((float4*)out)[i] = v;
    }
}

extern "C" void kernel_launch(void* const* d_in, const int* in_sizes, int n_in,
                              void* d_out, int out_size, void* d_ws, size_t ws_size,
                              hipStream_t stream) {
    const float* feats   = (const float*)d_in[0];
    const float* Wc      = (const float*)d_in[1];
    const float* Woff    = (const float*)d_in[2];
    const float* gamma   = (const float*)d_in[3];
    const float* beta    = (const float*)d_in[4];
    const int*   in_idx  = (const int*)d_in[5];
    const int*   out_idx = (const int*)d_in[6];
    const int P = in_sizes[5] / NOFF;

    char* w = (char*)d_ws;
    int* srcmap = (int*)w;                   w += (size_t)NOFF * NPAD * 4;    // 20.82 MB
    unsigned short* Wb = (unsigned short*)w; w += (size_t)27 * 6144 * 2;      // 332 KB
    float* pstats = (float*)w;               w += (size_t)192 * NBLK * 4;     // 0.6 MB
    float* scsh = (float*)w;                 w += 256 * 4;
    unsigned short* featsb = (unsigned short*)w;
    w += (size_t)(N_VOX + 1) * INC * 2;                                        // 25.6 MB (+pad row)
    unsigned short* stg = (unsigned short*)w;
    size_t need_stg = (size_t)(w - (char*)d_ws) + (size_t)N_VOX * OUTC * 2;   // +38.4 MB
    bool use_stg = (ws_size >= need_stg);

    hipMemsetAsync(srcmap, 0xFF, (size_t)NOFF * NPAD * 4, stream);
    hipMemsetAsync(featsb + (size_t)N_VOX * INC, 0, INC * 2, stream);         // zero pad row
    fill_src_kernel<<<(NOFF * P + 255) / 256, 256, 0, stream>>>(in_idx, out_idx, P, srcmap);
    wprep_kernel<<<(27 * 2 * 6 * 64 + 255) / 256, 256, 0, stream>>>(Wc, Woff, Wb);
    fcvt_kernel<<<(N_VOX * INC / 8 + 255) / 256, 256, 0, stream>>>(feats, featsb);

    float* out = (float*)d_out;
    if (use_stg) {
        conv_mfma_kernel<1><<<NBLK, 256, 0, stream>>>(featsb, Wb, srcmap, out, stg, pstats);
        stats_reduce_kernel<<<96, 256, 0, stream>>>(pstats, gamma, beta, scsh);
        apply_bn_bf16_kernel<<<2048, 256, 0, stream>>>(stg, out, scsh);
    } else {
        conv_mfma_kernel<0><<<NBLK, 256, 0, stream>>>(featsb, Wb, srcmap, out, stg, pstats);
        stats_reduce_kernel<<<96, 256, 0, stream>>>(pstats, gamma, beta, scsh);
        apply_bn_fp32_kernel<<<2048, 256, 0, stream>>>(out, scsh);
    }
}

// Round 9
// 119.255 us; speedup vs baseline: 1.3468x; 1.2251x over previous
//
#include <hip/hip_runtime.h>

// Sparse deconv (27-tap, 64->96ch) + BN + ReLU on MI355X.
// R3 structure (LDS-B dbuf via global_load_lds + per-tap barrier, exec-masked
// gathers, 2-deep srcmap prefetch) with M=48 rows/wave for 3 blocks/CU
// cross-block overlap, and bf16 conv-output staging.

#define N_VOX   200000
#define INC     64
#define OUTC    96
#define NOFF    26
#define MROWS   192           // rows per block (4 waves x 48)
#define NBLK    1042          // ceil(200000 / 192)
#define NPAD    200192        // >= NBLK*MROWS, padded srcmap stride
#define EPSV    1e-5f

using bf16x8 = __attribute__((ext_vector_type(8))) short;
using f32x4  = __attribute__((ext_vector_type(4))) float;

__device__ inline unsigned short f2bf(float x) {
    union { float f; unsigned u; } v; v.f = x;
    unsigned r = (v.u + 0x7FFFu + ((v.u >> 16) & 1u)) >> 16;
    return (unsigned short)r;
}

__device__ __forceinline__ void gload_lds16(const void* g, void* l) {
    __builtin_amdgcn_global_load_lds(
        (const __attribute__((address_space(1))) void*)g,
        (__attribute__((address_space(3))) void*)l, 16, 0, 0);
}

__global__ void fill_src_kernel(const int* __restrict__ in_idx,
                                const int* __restrict__ out_idx,
                                int P, int* __restrict__ srcmap) {
    int idx = blockIdx.x * blockDim.x + threadIdx.x;
    if (idx >= NOFF * P) return;
    int dst = out_idx[idx];
    if (dst >= N_VOX) return;            // padded sink entries
    int k = idx / P;
    srcmap[(size_t)k * NPAD + dst] = in_idx[idx];
}

// Weights -> bf16, B-fragment order: Wb[m][s][ct][lane][e],
// k = s*32 + (lane>>4)*8 + e, col = ct*16 + (lane&15).
__global__ void wprep_kernel(const float* __restrict__ Wc,
                             const float* __restrict__ Woff,
                             unsigned short* __restrict__ Wb) {
    int t = blockIdx.x * blockDim.x + threadIdx.x;
    if (t >= 27 * 2 * 6 * 64) return;
    int lane = t & 63;
    int g    = t >> 6;              // m*12 + s*6 + ct
    int ct   = g % 6;
    int s    = (g / 6) % 2;
    int m    = g / 12;
    const float* W = (m == 26) ? Wc : (Woff + (size_t)m * INC * OUTC);
    int k0 = s * 32 + (lane >> 4) * 8;
    int c  = ct * 16 + (lane & 15);
    bf16x8 v;
    #pragma unroll
    for (int e = 0; e < 8; ++e)
        v[e] = (short)f2bf(W[(size_t)(k0 + e) * OUTC + c]);
    *(bf16x8*)(Wb + (size_t)t * 8) = v;
}

__global__ void fcvt_kernel(const float* __restrict__ feats,
                            unsigned short* __restrict__ featsb) {
    int i = blockIdx.x * blockDim.x + threadIdx.x;   // one per 8 elems
    if (i >= N_VOX * INC / 8) return;
    const float4* src = (const float4*)feats + (size_t)i * 2;
    float4 f0 = src[0], f1 = src[1];
    bf16x8 v;
    v[0] = (short)f2bf(f0.x); v[1] = (short)f2bf(f0.y);
    v[2] = (short)f2bf(f0.z); v[3] = (short)f2bf(f0.w);
    v[4] = (short)f2bf(f1.x); v[5] = (short)f2bf(f1.y);
    v[6] = (short)f2bf(f1.z); v[7] = (short)f2bf(f1.w);
    *(bf16x8*)(featsb + (size_t)i * 8) = v;
}

// tap order: idx 0 -> center (Wb[26], identity src), idx i>=1 -> offset i-1.
template<int STAGE_BF16>
__global__ __launch_bounds__(256, 3)
void conv_mfma_kernel(const unsigned short* __restrict__ featsb,
                      const unsigned short* __restrict__ Wb,
                      const int* __restrict__ srcmap,
                      float* __restrict__ outf,
                      unsigned short* __restrict__ stg,
                      float* __restrict__ pstats) {
    __shared__ __align__(16) unsigned short Wlds[2][6144];   // 2 x 12 KB

    const int t     = threadIdx.x;
    const int wid   = t >> 6;
    const int lane  = t & 63;
    const int blk   = blockIdx.x;
    const int rbase = blk * MROWS + wid * 48;   // this wave's 48 output rows
    const int row16 = lane & 15;
    const int kgrp  = lane >> 4;                // 0..3

    f32x4  acc[3][6] = {};
    bf16x8 aC[3][2], aN[3][2];

    // ---- prologue ----
    // stage B for center tap into buf 0
    #pragma unroll
    for (int i = 0; i < 3; ++i)
        gload_lds16(Wb + (size_t)26 * 6144 + (size_t)(t + 256 * i) * 8,
                    &Wlds[0][(t + 256 * i) * 8]);

    // srcmap prefetch for tap 1 (offset 0): 1 coalesced load, lanes 0..47
    int sm_next = (lane < 48) ? srcmap[rbase + lane] : -1;

    // gather center rows -> aC (identity src; OOB rows read zeroed pad row)
    bool has_cur = false;
    #pragma unroll
    for (int rt = 0; rt < 3; ++rt) {
        int row = rbase + rt * 16 + row16;
        int src = row < N_VOX ? row : N_VOX;
        const unsigned short* fr = featsb + (size_t)src * INC + kgrp * 8;
        aC[rt][0] = *(const bf16x8*)fr;
        aC[rt][1] = *(const bf16x8*)(fr + 32);
        has_cur = true;
    }
    has_cur = __ballot(has_cur) != 0ull;
    __syncthreads();

    for (int idx = 0; idx < 27; ++idx) {
        const int buf = idx & 1;

        // 1. srcmap prefetch, 2 taps ahead (offset idx+1)
        int sm_next2 = -1;
        if (idx <= 24 && lane < 48)
            sm_next2 = srcmap[(size_t)(idx + 1) * NPAD + rbase + lane];

        // 2. gather A for next tap (offset idx, exec-masked) + stage its B
        bool has_next = false;
        if (idx <= 25) {
            bool any = false;
            #pragma unroll
            for (int rt = 0; rt < 3; ++rt) {
                int src = __shfl(sm_next, rt * 16 + row16);
                bf16x8 g0 = {}, g1 = {};
                if (src >= 0) {
                    const unsigned short* fr = featsb + (size_t)src * INC + kgrp * 8;
                    g0 = *(const bf16x8*)fr;
                    g1 = *(const bf16x8*)(fr + 32);
                    any = true;
                }
                aN[rt][0] = g0; aN[rt][1] = g1;
            }
            has_next = __ballot(any) != 0ull;
            #pragma unroll
            for (int i = 0; i < 3; ++i)
                gload_lds16(Wb + (size_t)idx * 6144 + (size_t)(t + 256 * i) * 8,
                            &Wlds[buf ^ 1][(t + 256 * i) * 8]);
        }

        // 3. MFMA current tap (B via ds_read; compiler inserts counted waits)
        if (has_cur) {
            const unsigned short* WL = Wlds[buf];
            #pragma unroll
            for (int ct = 0; ct < 6; ++ct) {
                bf16x8 b0 = *(const bf16x8*)&WL[(size_t)ct * 512 + lane * 8];
                bf16x8 b1 = *(const bf16x8*)&WL[(size_t)(6 + ct) * 512 + lane * 8];
                #pragma unroll
                for (int rt = 0; rt < 3; ++rt) {
                    acc[rt][ct] = __builtin_amdgcn_mfma_f32_16x16x32_bf16(aC[rt][0], b0, acc[rt][ct], 0, 0, 0);
                    acc[rt][ct] = __builtin_amdgcn_mfma_f32_16x16x32_bf16(aC[rt][1], b1, acc[rt][ct], 0, 0, 0);
                }
            }
        }
        __syncthreads();

        #pragma unroll
        for (int rt = 0; rt < 3; ++rt) { aC[rt][0] = aN[rt][0]; aC[rt][1] = aN[rt][1]; }
        sm_next = sm_next2;
        has_cur = has_next;
    }

    // ---- BN partial stats: lane -> wave shfl -> LDS cross-wave ----
    float s6[6], q6[6];
    #pragma unroll
    for (int ct = 0; ct < 6; ++ct) {
        float s = 0.f, q = 0.f;
        #pragma unroll
        for (int rt = 0; rt < 3; ++rt) {
            f32x4 a = acc[rt][ct];
            s += a[0] + a[1] + a[2] + a[3];
            q += a[0]*a[0] + a[1]*a[1] + a[2]*a[2] + a[3]*a[3];
        }
        s += __shfl_xor(s, 16); q += __shfl_xor(q, 16);
        s += __shfl_xor(s, 32); q += __shfl_xor(q, 32);
        s6[ct] = s; q6[ct] = q;
    }
    float* sred = (float*)Wlds;      // reuse LDS (post final barrier)
    if (lane < 16) {
        #pragma unroll
        for (int ct = 0; ct < 6; ++ct) {
            sred[wid * 96 + ct * 16 + lane]       = s6[ct];
            sred[384 + wid * 96 + ct * 16 + lane] = q6[ct];
        }
    }
    __syncthreads();
    if (t < 96) {
        float s = sred[t] + sred[96 + t] + sred[192 + t] + sred[288 + t];
        pstats[(size_t)t * NBLK + blk] = s;
    } else if (t < 192) {
        int c = t - 96;
        float q = sred[384 + c] + sred[480 + c] + sred[576 + c] + sred[672 + c];
        pstats[(size_t)(96 + c) * NBLK + blk] = q;
    }

    // ---- store conv output ----
    #pragma unroll
    for (int rt = 0; rt < 3; ++rt) {
        #pragma unroll
        for (int ct = 0; ct < 6; ++ct) {
            #pragma unroll
            for (int j = 0; j < 4; ++j) {
                int row = rbase + rt * 16 + kgrp * 4 + j;
                if (row < N_VOX) {
                    if (STAGE_BF16)
                        stg[(size_t)row * OUTC + ct * 16 + row16] = f2bf(acc[rt][ct][j]);
                    else
                        outf[(size_t)row * OUTC + ct * 16 + row16] = acc[rt][ct][j];
                }
            }
        }
    }
}

__global__ void stats_reduce_kernel(const float* __restrict__ pstats,
                                    const float* __restrict__ gamma,
                                    const float* __restrict__ beta,
                                    float* __restrict__ scsh) {
    int c = blockIdx.x;               // 0..95
    int t = threadIdx.x;
    float s = 0.f, q = 0.f;
    for (int i = t; i < NBLK; i += 256) {
        s += pstats[(size_t)c * NBLK + i];
        q += pstats[(size_t)(96 + c) * NBLK + i];
    }
    #pragma unroll
    for (int d = 1; d < 64; d <<= 1) {
        s += __shfl_xor(s, d);
        q += __shfl_xor(q, d);
    }
    __shared__ float rs[4], rq[4];
    if ((t & 63) == 0) { rs[t >> 6] = s; rq[t >> 6] = q; }
    __syncthreads();
    if (t == 0) {
        s = rs[0] + rs[1] + rs[2] + rs[3];
        q = rq[0] + rq[1] + rq[2] + rq[3];
        float inv_n = 1.0f / (float)N_VOX;
        float mean = s * inv_n;
        float var  = q * inv_n - mean * mean;
        float sc   = gamma[c] * rsqrtf(var + EPSV);
        scsh[c]      = sc;
        scsh[96 + c] = beta[c] - mean * sc;
    }
}

__global__ void apply_bn_bf16_kernel(const unsigned short* __restrict__ stg,
                                     float* __restrict__ out,
                                     const float* __restrict__ scsh) {
    __shared__ float sc[OUTC], sh[OUTC];
    int t = threadIdx.x;
    if (t < OUTC) { sc[t] = scsh[t]; sh[t] = scsh[96 + t]; }
    __syncthreads();
    const int total8 = N_VOX * OUTC / 8;
    for (int i = blockIdx.x * blockDim.x + t; i < total8; i += gridDim.x * blockDim.x) {
        bf16x8 v = *(const bf16x8*)(stg + (size_t)i * 8);
        int c = (i % 12) * 8;
        float o[8];
        #pragma unroll
        for (int j = 0; j < 8; ++j) {
            union { unsigned u; float f; } w; w.u = (unsigned)(unsigned short)v[j] << 16;
            o[j] = fmaxf(fmaf(w.f, sc[c + j], sh[c + j]), 0.f);
        }
        float4* dst = (float4*)(out + (size_t)i * 8);
        dst[0] = make_float4(o[0], o[1], o[2], o[3]);
        dst[1] = make_float4(o[4], o[5], o[6], o[7]);
    }
}

__global__ void apply_bn_fp32_kernel(float* __restrict__ out,
                                     const float* __restrict__ scsh) {
    __shared__ float sc[OUTC], sh[OUTC];
    int t = threadIdx.x;
    if (t < OUTC) { sc[t] = scsh[t]; sh[t] = scsh[96 + t]; }
    __syncthreads();
    const int total4 = N_VOX * OUTC / 4;
    for (int i = blockIdx.x * blockDim.x + t; i < total4; i += gridDim.x * blockDim.x) {
        float4 v = ((float4*)out)[i];
        int c = (i * 4) % OUTC;
        v.x = fmaxf(fmaf(v.x, sc[c    ], sh[c    ]), 0.f);
        v.y = fmaxf(fmaf(v.y, sc[c + 1], sh[c + 1]), 0.f);
        v.z = fmaxf(fmaf(v.z, sc[c + 2], sh[c + 2]), 0.f);
        v.w = fmaxf(fmaf(v.w, sc[c + 3], sh[c + 3]), 0.f);
        ((float4*)out)[i] = v;
    }
}

extern "C" void kernel_launch(void* const* d_in, const int* in_sizes, int n_in,
                              void* d_out, int out_size, void* d_ws, size_t ws_size,
                              hipStream_t stream) {
    const float* feats   = (const float*)d_in[0];
    const float* Wc      = (const float*)d_in[1];
    const float* Woff    = (const float*)d_in[2];
    const float* gamma   = (const float*)d_in[3];
    const float* beta    = (const float*)d_in[4];
    const int*   in_idx  = (const int*)d_in[5];
    const int*   out_idx = (const int*)d_in[6];
    const int P = in_sizes[5] / NOFF;

    char* w = (char*)d_ws;
    int* srcmap = (int*)w;                   w += (size_t)NOFF * NPAD * 4;    // 20.82 MB
    unsigned short* Wb = (unsigned short*)w; w += (size_t)27 * 6144 * 2;      // 332 KB
    float* pstats = (float*)w;               w += (size_t)192 * NBLK * 4;     // 0.8 MB
    float* scsh = (float*)w;                 w += 256 * 4;
    unsigned short* featsb = (unsigned short*)w;
    w += (size_t)(N_VOX + 1) * INC * 2;                                        // 25.6 MB (+pad row)
    unsigned short* stg = (unsigned short*)w;
    size_t need_stg = (size_t)(w - (char*)d_ws) + (size_t)N_VOX * OUTC * 2;   // +38.4 MB
    bool use_stg = (ws_size >= need_stg);

    hipMemsetAsync(srcmap, 0xFF, (size_t)NOFF * NPAD * 4, stream);
    hipMemsetAsync(featsb + (size_t)N_VOX * INC, 0, INC * 2, stream);         // zero pad row
    fill_src_kernel<<<(NOFF * P + 255) / 256, 256, 0, stream>>>(in_idx, out_idx, P, srcmap);
    wprep_kernel<<<(27 * 2 * 6 * 64 + 255) / 256, 256, 0, stream>>>(Wc, Woff, Wb);
    fcvt_kernel<<<(N_VOX * INC / 8 + 255) / 256, 256, 0, stream>>>(feats, featsb);

    float* out = (float*)d_out;
    if (use_stg) {
        conv_mfma_kernel<1><<<NBLK, 256, 0, stream>>>(featsb, Wb, srcmap, out, stg, pstats);
        stats_reduce_kernel<<<96, 256, 0, stream>>>(pstats, gamma, beta, scsh);
        apply_bn_bf16_kernel<<<2048, 256, 0, stream>>>(stg, out, scsh);
    } else {
        conv_mfma_kernel<0><<<NBLK, 256, 0, stream>>>(featsb, Wb, srcmap, out, stg, pstats);
        stats_reduce_kernel<<<96, 256, 0, stream>>>(pstats, gamma, beta, scsh);
        apply_bn_fp32_kernel<<<2048, 256, 0, stream>>>(out, scsh);
    }
}